// Round 5
// baseline (1941.309 us; speedup 1.0000x reference)
//
#include <hip/hip_runtime.h>
#include <stdint.h>

#define T_STEPS 1024
#define BATCH   512
#define IN_DIM  64
#define HID_DIM 256
#define OUT_DIM 32

// ---------------------------------------------------------------------------
// Bit-replication of the numpy fp32 reference.
//   cur = BLAS sgemm dot: single fp32 accumulator, k ascending, fmaf each
//         step, bias added afterwards as a separately-rounded fp32 add.
//   LIF:  mem = ((0.92f*mem) + cur) - reset   -- three separate fp32 ops.
// Layout: one block per batch b, 320 threads.
//   tid 0..255  : layer-1 unit h. W1 row in regs; x_t double-buffered in LDS.
//   tid 256..287: layer-2 output o, LAGGED ONE STEP (overlaps layer-1(t+1));
//                 reads spk1 from double-buffered LDS, W2 from LDS [k][o].
// One __syncthreads per step. Outputs fp32: [spk2; mem2], each [T,B,32].
// ---------------------------------------------------------------------------
__global__ __launch_bounds__(320, 2) void snn_fp32_kernel(
    const float* __restrict__ x,    // [T,B,64]
    const float* __restrict__ W1,   // [256,64]
    const float* __restrict__ b1,   // [256]
    const float* __restrict__ W2,   // [32,256]
    const float* __restrict__ b2,   // [32]
    float* __restrict__ out_spk,    // [T,B,32]
    float* __restrict__ out_mem)    // [T,B,32]
{
    const int b   = blockIdx.x;
    const int tid = threadIdx.x;

    __shared__ float xbuf[2][IN_DIM];
    __shared__ float spkbuf[2][HID_DIM];
    __shared__ float w2s[HID_DIM][OUT_DIM];   // transposed: [k][o], o = fast idx

    // cooperative one-time load of W2 (global [o][k] coalesced) -> LDS [k][o]
    for (int i = tid; i < HID_DIM * OUT_DIM; i += 320) {
        const int o = i / HID_DIM, k = i % HID_DIM;
        w2s[k][o] = W2[i];
    }
    if (tid < IN_DIM) xbuf[0][tid] = x[(size_t)b * IN_DIM + tid];

    float w1r[IN_DIM];
    float bias1 = 0.f, mem1 = 0.f;
    float bias2 = 0.f, mem2 = 0.f;
    if (tid < HID_DIM) {
#pragma unroll
        for (int k = 0; k < IN_DIM; ++k) w1r[k] = W1[tid * IN_DIM + k];
        bias1 = b1[tid];
    } else if (tid < HID_DIM + OUT_DIM) {
        bias2 = b2[tid - HID_DIM];
    }
    __syncthreads();

    for (int t = 0; t <= T_STEPS; ++t) {
        if (tid < HID_DIM) {
            if (t < T_STEPS) {
                // ---- layer 1, step t: sequential-k fp32 FMA chain ----
                const float* xb = xbuf[t & 1];
                float acc = 0.0f;
#pragma unroll
                for (int k = 0; k < IN_DIM; ++k)
                    acc = fmaf(xb[k], w1r[k], acc);        // BLAS order
                const float cur1 = __fadd_rn(acc, bias1);  // separate bias add
                const float r1 = (mem1 > 1.0f) ? 1.0f : 0.0f;  // prev-mem reset
                mem1 = __fsub_rn(__fadd_rn(__fmul_rn(0.92f, mem1), cur1), r1);
                spkbuf[t & 1][tid] = (mem1 > 1.0f) ? 1.0f : 0.0f;
                // prefetch x(t+1) into the other buffer
                if (tid < IN_DIM && t + 1 < T_STEPS)
                    xbuf[(t + 1) & 1][tid] =
                        x[((size_t)(t + 1) * BATCH + b) * IN_DIM + tid];
            }
        } else if (tid < HID_DIM + OUT_DIM && t > 0) {
            // ---- layer 2, step t-1 (lagged): sequential-k fp32 FMA chain ----
            const int o  = tid - HID_DIM;
            const int tt = t - 1;
            const float* sb = spkbuf[tt & 1];
            float acc = 0.0f;
#pragma unroll 16
            for (int k = 0; k < HID_DIM; ++k)
                acc = fmaf(sb[k], w2s[k][o], acc);         // BLAS order
            const float cur2 = __fadd_rn(acc, bias2);
            const float r2 = (mem2 > 1.0f) ? 1.0f : 0.0f;
            mem2 = __fsub_rn(__fadd_rn(__fmul_rn(0.92f, mem2), cur2), r2);
            const size_t idx = ((size_t)tt * BATCH + b) * OUT_DIM + o;
            out_spk[idx] = (mem2 > 1.0f) ? 1.0f : 0.0f;
            out_mem[idx] = mem2;
        }
        __syncthreads();
        // races checked: spkbuf[q] written at iter t, read at iter t+1,
        // overwritten at iter t+2 -- always separated by >=1 barrier.
    }
}

extern "C" void kernel_launch(void* const* d_in, const int* in_sizes, int n_in,
                              void* d_out, int out_size, void* d_ws, size_t ws_size,
                              hipStream_t stream) {
    const float* x  = (const float*)d_in[0];  // [T,B,64] fp32
    const float* W1 = (const float*)d_in[1];  // [256,64] fp32
    const float* b1 = (const float*)d_in[2];  // [256]    fp32
    const float* W2 = (const float*)d_in[3];  // [32,256] fp32
    const float* b2 = (const float*)d_in[4];  // [32]     fp32

    float* out_spk = (float*)d_out;                       // fp32 outputs
    float* out_mem = out_spk + (size_t)T_STEPS * BATCH * OUT_DIM;

    snn_fp32_kernel<<<BATCH, 320, 0, stream>>>(x, W1, b1, W2, b2,
                                               out_spk, out_mem);
}

// Round 6
// 1436.928 us; speedup vs baseline: 1.3510x; 1.3510x over previous
//
#include <hip/hip_runtime.h>
#include <stdint.h>

#define T_STEPS 1024
#define BATCH   512
#define IN_DIM  64
#define HID_DIM 256
#define OUT_DIM 32

// ===========================================================================
// NUMERICS CONTRACT (validated by R4 pass, absmax 7.8e-3 vs 5.75e-2):
//   * dot products: single fp32 accumulator, k ASCENDING, fmaf each step
//   * bias: separately-rounded fp32 add AFTER the chain
//   * LIF: mem = ((0.92f*mem) + cur) - reset, three separate fp32 ops,
//          reset from PREVIOUS mem, compares mem > 1.0f
// Any reassociation flips spikes (binary outputs, 16.7M decisions). Do not.
// ===========================================================================

// ---------------------------------------------------------------------------
// Phase 1: fused GEMM1 + LIF1. Thread = (b,h); t sequential per thread.
// x_t row is wave-uniform -> compiler emits scalar loads / broadcast loads;
// double-buffered in registers one step ahead. spk1 exported as ballot bits.
// No LDS, no barriers.
// ---------------------------------------------------------------------------
__global__ __launch_bounds__(256, 2) void snn_l1(
    const float* __restrict__ x,                  // [T,B,64]
    const float* __restrict__ W1,                 // [256,64]
    const float* __restrict__ b1,                 // [256]
    unsigned long long* __restrict__ bits)        // [T,B,4] u64 ballots
{
    const int b    = blockIdx.x;
    const int h    = threadIdx.x;
    const int wv   = h >> 6;
    const int lane = h & 63;

    float w1r[IN_DIM];
#pragma unroll
    for (int k = 0; k < IN_DIM; ++k) w1r[k] = W1[h * IN_DIM + k];
    const float bias1 = b1[h];

    const float4* xrow  = (const float4*)(x + (size_t)b * IN_DIM);
    const size_t  xstep = (size_t)BATCH * IN_DIM / 4;   // float4 stride per t

    float4 xa[16], xb[16];
#pragma unroll
    for (int i = 0; i < 16; ++i) xa[i] = xrow[i];       // t = 0

    float mem1 = 0.0f;

#define L1_STEP(CUR, NXT, T)                                               \
    {                                                                      \
        if ((T) + 1 < T_STEPS) {                                           \
            const float4* xp = xrow + (size_t)((T) + 1) * xstep;           \
            _Pragma("unroll")                                              \
            for (int i = 0; i < 16; ++i) NXT[i] = xp[i];                   \
        }                                                                  \
        float acc = 0.0f;                                                  \
        _Pragma("unroll")                                                  \
        for (int i = 0; i < 16; ++i) {                                     \
            acc = fmaf(CUR[i].x, w1r[4 * i + 0], acc);                     \
            acc = fmaf(CUR[i].y, w1r[4 * i + 1], acc);                     \
            acc = fmaf(CUR[i].z, w1r[4 * i + 2], acc);                     \
            acc = fmaf(CUR[i].w, w1r[4 * i + 3], acc);                     \
        }                                                                  \
        const float cur1 = __fadd_rn(acc, bias1);                          \
        const float r1 = (mem1 > 1.0f) ? 1.0f : 0.0f;                      \
        mem1 = __fsub_rn(__fadd_rn(__fmul_rn(0.92f, mem1), cur1), r1);     \
        const unsigned long long bm = __ballot(mem1 > 1.0f);               \
        if (lane == 0)                                                     \
            bits[((size_t)(T) * BATCH + b) * 4 + wv] = bm;                 \
    }

    for (int t = 0; t < T_STEPS; t += 2) {
        L1_STEP(xa, xb, t)
        L1_STEP(xb, xa, t + 1)
    }
#undef L1_STEP
}

// ---------------------------------------------------------------------------
// Phase 2: GEMM2 over all (t,b,o) in parallel. Lane = one (t,b), 4 outputs
// o = og*4..og*4+3 (og = blockIdx.y, wave-uniform -> W2 rows via scalar
// loads). Spikes as 8 u32 bit-words per lane; per k: bfe + cvt + 4 fmac.
// Exact k-ascending chain per output preserved. Stores cur2 (+bias).
// ---------------------------------------------------------------------------
__global__ __launch_bounds__(256, 4) void snn_l2gemm(
    const uint32_t* __restrict__ bits,   // [T*B, 8] u32
    const float* __restrict__ W2,        // [32,256]
    const float* __restrict__ b2,        // [32]
    float* __restrict__ cur2)            // [T*B, 32]
{
    const int    og = blockIdx.y;                              // 0..7
    const size_t tb = (size_t)blockIdx.x * 256 + threadIdx.x;  // 0..T*B-1

    const uint4 wA = ((const uint4*)bits)[tb * 2 + 0];
    const uint4 wB = ((const uint4*)bits)[tb * 2 + 1];
    const uint32_t wds[8] = {wA.x, wA.y, wA.z, wA.w, wB.x, wB.y, wB.z, wB.w};

    const float* __restrict__ wr0 = W2 + (og * 4 + 0) * HID_DIM;
    const float* __restrict__ wr1 = W2 + (og * 4 + 1) * HID_DIM;
    const float* __restrict__ wr2 = W2 + (og * 4 + 2) * HID_DIM;
    const float* __restrict__ wr3 = W2 + (og * 4 + 3) * HID_DIM;

    float a0 = 0.0f, a1 = 0.0f, a2 = 0.0f, a3 = 0.0f;

#pragma unroll
    for (int c = 0; c < 16; ++c) {            // 16 chunks x 16 k
        float r0[16], r1[16], r2[16], r3[16];
#pragma unroll
        for (int i = 0; i < 16; ++i) {
            const int k = c * 16 + i;
            r0[i] = wr0[k];                   // wave-uniform -> s_load
            r1[i] = wr1[k];
            r2[i] = wr2[k];
            r3[i] = wr3[k];
        }
        const uint32_t word = wds[c >> 1];
        const int      base = (c & 1) * 16;
#pragma unroll
        for (int i = 0; i < 16; ++i) {
            const float sf = (float)((word >> (base + i)) & 1u);  // 0.0 / 1.0
            a0 = fmaf(sf, r0[i], a0);         // exact: == fl(acc + w) or acc
            a1 = fmaf(sf, r1[i], a1);
            a2 = fmaf(sf, r2[i], a2);
            a3 = fmaf(sf, r3[i], a3);
        }
    }

    a0 = __fadd_rn(a0, b2[og * 4 + 0]);       // separately-rounded bias add
    a1 = __fadd_rn(a1, b2[og * 4 + 1]);
    a2 = __fadd_rn(a2, b2[og * 4 + 2]);
    a3 = __fadd_rn(a3, b2[og * 4 + 3]);

    ((float4*)cur2)[tb * (OUT_DIM / 4) + og] = make_float4(a0, a1, a2, a3);
}

// ---------------------------------------------------------------------------
// Phase 3: LIF2 t-scan. Thread = (b,o), 16384 chains. Reads cur2 in-place
// from the out_spk region and overwrites it with spk2; mem2 to out_mem
// (which also overwrites the by-now-consumed bits scratch). 8-deep load
// batching to keep HBM/L3 requests in flight.
// ---------------------------------------------------------------------------
__global__ __launch_bounds__(256, 4) void snn_l2scan(
    float* __restrict__ spk_io,          // [T,B,32]: cur2 in, spk2 out
    float* __restrict__ mem_out)         // [T,B,32]
{
    const int tid = threadIdx.x;
    const int o   = tid & (OUT_DIM - 1);
    const int b   = blockIdx.x * 8 + (tid >> 5);

    float* p = spk_io  + (size_t)b * OUT_DIM + o;
    float* m = mem_out + (size_t)b * OUT_DIM + o;
    const size_t step = (size_t)BATCH * OUT_DIM;

    float mem2 = 0.0f;
    for (int t = 0; t < T_STEPS; t += 8) {
        float c[8];
#pragma unroll
        for (int u = 0; u < 8; ++u) c[u] = p[(size_t)(t + u) * step];
#pragma unroll
        for (int u = 0; u < 8; ++u) {
            const float r2 = (mem2 > 1.0f) ? 1.0f : 0.0f;
            mem2 = __fsub_rn(__fadd_rn(__fmul_rn(0.92f, mem2), c[u]), r2);
            p[(size_t)(t + u) * step] = (mem2 > 1.0f) ? 1.0f : 0.0f;
            m[(size_t)(t + u) * step] = mem2;
        }
    }
}

extern "C" void kernel_launch(void* const* d_in, const int* in_sizes, int n_in,
                              void* d_out, int out_size, void* d_ws, size_t ws_size,
                              hipStream_t stream) {
    const float* x  = (const float*)d_in[0];  // [T,B,64] fp32
    const float* W1 = (const float*)d_in[1];  // [256,64] fp32
    const float* b1 = (const float*)d_in[2];  // [256]    fp32
    const float* W2 = (const float*)d_in[3];  // [32,256] fp32
    const float* b2 = (const float*)d_in[4];  // [32]     fp32

    float* out_spk = (float*)d_out;                                  // 67 MB
    float* out_mem = out_spk + (size_t)T_STEPS * BATCH * OUT_DIM;    // 67 MB

    // Scratch plan (zero d_ws usage):
    //   bits (16 MB) live at the start of out_mem; consumed entirely by
    //   phase 2 before phase 3 overwrites that region with mem2.
    //   cur2 lives in out_spk; phase 3 overwrites it in-place with spk2.
    unsigned long long* bits = (unsigned long long*)out_mem;

    snn_l1<<<BATCH, 256, 0, stream>>>(x, W1, b1, bits);

    dim3 g2(T_STEPS * BATCH / 256, 8);
    snn_l2gemm<<<g2, 256, 0, stream>>>((const uint32_t*)bits, W2, b2, out_spk);

    snn_l2scan<<<BATCH / 8, 256, 0, stream>>>(out_spk, out_mem);
}